// Round 10
// baseline (43.002 us; speedup 1.0000x reference)
//
#include <hip/hip_runtime.h>
#include <hip/hip_bf16.h>

// Problem constants (B, T, C, HS) from the reference.
#define NB 256
#define NT 256
#define NC 384
#define NH 64
#define NW 192              // 3 * NH concatenated output cols
#define WT_ELEMS (NW * NC)  // Wt bf16 elements = 73728

typedef short bf16x8 __attribute__((ext_vector_type(8)));
typedef float f32x4 __attribute__((ext_vector_type(4)));

__device__ __forceinline__ unsigned short f2bf(float f) {
  union { float f; unsigned int i; } c;
  c.f = f;
  const unsigned int r = c.i + 0x7fffu + ((c.i >> 16) & 1u);
  return (unsigned short)(r >> 16);
}

__device__ __forceinline__ unsigned short f2bf_hw(float f) {
  __hip_bfloat16 b = __float2bfloat16(f);
  return *reinterpret_cast<unsigned short*>(&b);
}

// ---------------------------------------------------------------------------
// Kernel 0: transpose + convert weights. Wt[n][k] bf16 [192][384].
// ---------------------------------------------------------------------------
__global__ __launch_bounds__(256) void w_transpose_kernel(
    const float* __restrict__ Wq,
    const float* __restrict__ Wk,
    const float* __restrict__ Wv,
    unsigned short* __restrict__ Wt) {
  const int idx = blockIdx.x * 256 + threadIdx.x;
  if (idx >= WT_ELEMS) return;
  const int n = idx / NC, k = idx - n * NC;
  const float* W = (n < 64) ? Wq : (n < 128) ? Wk : Wv;
  Wt[idx] = f2bf(W[k * NH + (n & 63)]);
}

// ---------------------------------------------------------------------------
// Kernel 1 (round 10): fused proj+attn, REG-STAGED pipeline (T14).
//
// Round-9 post-mortem: loop streams at ~5.1 TB/s mixed while HBM-only
// portion is just 66 MB (~10.5 us) — waves park at vmcnt despite 96 KB/CU
// nominally in flight. Hypothesis: global_load_lds DMA queue caps per-CU
// concurrency. This round: plain global_load_dwordx4 -> regs -> cvt bf16
// -> ds_write (compiler-tracked waits, deep VMEM queue). Bundled certain
// wins: 1 barrier/step (tile t+1 written to the OTHER LDS buffer during
// compute of t), bf16 x in LDS (A-frag = one b128, cvt once), padded
// stride-40 rows (bank starts 20r+4lg mod 32 -> 2-way = free).
//
// Pipeline (12 tiles, BK=32; per-thread per-tile: 4 x-loads + 2 W-loads):
//   prologue: RLOAD(A,0); RLOAD(B,1); WRITE(buf0,A); lgkm0; barrier
//   step t (t=0..11): RLOAD(S(t), t+2) | WRITE(buf[(t+1)&1], S(t+1)) |
//                     COMPUTE(buf[t&1]) | lgkm0 | barrier
//   S(t) = pA for even t. Reg WAR/load waits handled by compiler dataflow.
//
// LDS map (proj): Xbuf 2 x 20480 B ([256][40] bf16), Wbuf 2 x 15360 B
// ([192][40] bf16) = 71680 B. Attn phase reuses [0,118784) as round 9:
// Kls 32K | Vtls 32K | Qls 32K | Pls 20K.
// mfma_f32_16x16x32_bf16 layouts (HW-verified round 2):
//   A/B: k = (l>>4)*8+j contiguous;  D: n = l&15, m = (l>>4)*4 + r.
// ---------------------------------------------------------------------------
__global__ __launch_bounds__(512, 2) void fused_qkv_attn_kernel(
    const float* __restrict__ x,
    const unsigned short* __restrict__ Wt,
    float* __restrict__ out) {
  __shared__ __align__(16) unsigned char lds[118784];

  const int tid = threadIdx.x;
  const int w = tid >> 6;
  const int lane = tid & 63;
  const int l15 = lane & 15;
  const int lg = lane >> 4;
  const int b = blockIdx.x;
  const int row0 = b * NT;              // this block's 256 x-rows
  const int qt = (w < 4) ? w : 11 - w;  // causal-balanced q-tile per wave
  const int wbase = qt * 32;            // wave's 32 rows (block-local)

  f32x4 acc[2][12];
#pragma unroll
  for (int mi = 0; mi < 2; ++mi)
#pragma unroll
    for (int ni = 0; ni < 12; ++ni)
#pragma unroll
      for (int r = 0; r < 4; ++r) acc[mi][ni][r] = 0.f;

  // ---- per-thread staging coordinates (computed once) ----
  // x: 2048 chunks of 4 fp32; chunk idx = j*512+tid: row=idx>>3, c=idx&7.
  int xrow[4], xcol[4];
#pragma unroll
  for (int j = 0; j < 4; ++j) {
    const int idx = j * 512 + tid;
    xrow[j] = idx >> 3;
    xcol[j] = idx & 7;
  }
  // W: 768 chunks of 8 bf16; idx = tid, then 512+tid remapped (dupes 512..767
  // written twice with identical data - benign).
  int wnr[2], wcc[2];
  {
    const int i0 = tid;
    const int raw = 512 + tid;
    const int i1 = (raw < 768) ? raw : raw - 256;
    wnr[0] = i0 >> 2; wcc[0] = i0 & 3;
    wnr[1] = i1 >> 2; wcc[1] = i1 & 3;
  }

  // Register tile sets (static names - rule #20).
  float4 xA0, xA1, xA2, xA3, xB0, xB1, xB2, xB3;
  bf16x8 wA0, wA1, wB0, wB1;

#define XL(BUF) reinterpret_cast<unsigned short*>(lds + (BUF)*20480)
#define WL(BUF) reinterpret_cast<unsigned short*>(lds + 40960 + (BUF)*15360)

#define RLOAD(S, KT)                                                          \
  do {                                                                        \
    x##S##0 = *reinterpret_cast<const float4*>(                               \
        x + (size_t)(row0 + xrow[0]) * NC + (KT)*32 + xcol[0] * 4);           \
    x##S##1 = *reinterpret_cast<const float4*>(                               \
        x + (size_t)(row0 + xrow[1]) * NC + (KT)*32 + xcol[1] * 4);           \
    x##S##2 = *reinterpret_cast<const float4*>(                               \
        x + (size_t)(row0 + xrow[2]) * NC + (KT)*32 + xcol[2] * 4);           \
    x##S##3 = *reinterpret_cast<const float4*>(                               \
        x + (size_t)(row0 + xrow[3]) * NC + (KT)*32 + xcol[3] * 4);           \
    w##S##0 = *reinterpret_cast<const bf16x8*>(                               \
        Wt + (size_t)wnr[0] * NC + (KT)*32 + wcc[0] * 8);                     \
    w##S##1 = *reinterpret_cast<const bf16x8*>(                               \
        Wt + (size_t)wnr[1] * NC + (KT)*32 + wcc[1] * 8);                     \
  } while (0)

#define WRX(BUF, V, J)                                                        \
  do {                                                                        \
    ushort4 t_;                                                               \
    t_.x = f2bf_hw((V).x); t_.y = f2bf_hw((V).y);                             \
    t_.z = f2bf_hw((V).z); t_.w = f2bf_hw((V).w);                             \
    *reinterpret_cast<ushort4*>(XL(BUF) + xrow[J] * 40 + xcol[J] * 4) = t_;   \
  } while (0)

#define WRITE(BUF, S)                                                         \
  do {                                                                        \
    WRX(BUF, x##S##0, 0); WRX(BUF, x##S##1, 1);                               \
    WRX(BUF, x##S##2, 2); WRX(BUF, x##S##3, 3);                               \
    *reinterpret_cast<bf16x8*>(WL(BUF) + wnr[0] * 40 + wcc[0] * 8) = w##S##0; \
    *reinterpret_cast<bf16x8*>(WL(BUF) + wnr[1] * 40 + wcc[1] * 8) = w##S##1; \
  } while (0)

#define COMPUTE(BUF)                                                          \
  do {                                                                        \
    const unsigned short* Xc = XL(BUF);                                       \
    const unsigned short* Wc = WL(BUF);                                       \
    const bf16x8 afr0 = *reinterpret_cast<const bf16x8*>(                     \
        Xc + (wbase + l15) * 40 + lg * 8);                                    \
    const bf16x8 afr1 = *reinterpret_cast<const bf16x8*>(                     \
        Xc + (wbase + 16 + l15) * 40 + lg * 8);                               \
    _Pragma("unroll") for (int ni = 0; ni < 12; ++ni) {                       \
      const bf16x8 bfr = *reinterpret_cast<const bf16x8*>(                    \
          Wc + (ni * 16 + l15) * 40 + lg * 8);                                \
      acc[0][ni] = __builtin_amdgcn_mfma_f32_16x16x32_bf16(                   \
          afr0, bfr, acc[0][ni], 0, 0, 0);                                    \
      acc[1][ni] = __builtin_amdgcn_mfma_f32_16x16x32_bf16(                   \
          afr1, bfr, acc[1][ni], 0, 0, 0);                                    \
    }                                                                         \
  } while (0)

#define STEP(T, CUR, NXT, L2, W1)                                             \
  do {                                                                        \
    if (L2) RLOAD(CUR, (T) + 2);                                              \
    if (W1) WRITE(((T) + 1) & 1, NXT);                                        \
    COMPUTE((T)&1);                                                           \
    asm volatile("s_waitcnt lgkmcnt(0)" ::: "memory");                        \
    __builtin_amdgcn_s_barrier();                                             \
  } while (0)

  // ---- prologue ----
  RLOAD(A, 0);
  RLOAD(B, 1);
  WRITE(0, A);  // compiler waits for A regs (B stays in flight)
  asm volatile("s_waitcnt lgkmcnt(0)" ::: "memory");
  __builtin_amdgcn_s_barrier();

  // ---- 12 steps (S(t)=A for even t; tile t+1 regs written during step t) --
  STEP(0, A, B, 1, 1);
  STEP(1, B, A, 1, 1);
  STEP(2, A, B, 1, 1);
  STEP(3, B, A, 1, 1);
  STEP(4, A, B, 1, 1);
  STEP(5, B, A, 1, 1);
  STEP(6, A, B, 1, 1);
  STEP(7, B, A, 1, 1);
  STEP(8, A, B, 1, 1);
  STEP(9, B, A, 1, 1);
  STEP(10, A, B, 0, 1);
  STEP(11, B, A, 0, 0);

  // ---- epilogue: scatter acc into attention LDS layouts (bf16) ----
  unsigned short* Kls = reinterpret_cast<unsigned short*>(lds);           // 32K
  unsigned short* Vtls = reinterpret_cast<unsigned short*>(lds + 32768);  // 32K
  unsigned short* Qls = reinterpret_cast<unsigned short*>(lds + 65536);   // 32K
  unsigned short* Pls = reinterpret_cast<unsigned short*>(lds + 98304);   // 20K

#pragma unroll
  for (int mi = 0; mi < 2; ++mi)
#pragma unroll
    for (int ni = 0; ni < 12; ++ni) {
      const int n = ni * 16 + l15;
#pragma unroll
      for (int r = 0; r < 4; ++r) {
        const int srow = wbase + mi * 16 + lg * 4 + r;
        const unsigned short val = f2bf_hw(acc[mi][ni][r]);
        if (ni < 4) {
          Qls[srow * 64 + (n ^ ((srow & 7) << 3))] = val;
        } else if (ni < 8) {
          const int h = n - 64;
          Kls[srow * 64 + (h ^ ((srow & 7) << 3))] = val;
        } else {
          const int h = n - 128;
          Vtls[h * 256 + (srow ^ ((h & 7) << 3))] = val;
        }
      }
    }
  __syncthreads();

  // ---- attention phase (flash, per-wave independent; unchanged) ----
  const int q0 = wbase;
  bf16x8 a_q[2][2];
#pragma unroll
  for (int mi = 0; mi < 2; ++mi)
#pragma unroll
    for (int ks = 0; ks < 2; ++ks) {
      const int srow = q0 + mi * 16 + l15;
      a_q[mi][ks] = *reinterpret_cast<const bf16x8*>(
          Qls + srow * 64 + ((ks * 32 + lg * 8) ^ ((srow & 7) << 3)));
    }

  f32x4 o[2][4];
  float mrun[2][4], lrun[2][4];
#pragma unroll
  for (int mi = 0; mi < 2; ++mi)
#pragma unroll
    for (int r = 0; r < 4; ++r) {
      mrun[mi][r] = -3.0e38f;
      lrun[mi][r] = 0.f;
#pragma unroll
      for (int hi = 0; hi < 4; ++hi) o[mi][hi][r] = 0.f;
    }

  unsigned short* Pw = Pls + w * 1280;  // per-wave [32][40]

  for (int j = 0; j <= qt; ++j) {
    f32x4 s_acc[2][2];
#pragma unroll
    for (int mi = 0; mi < 2; ++mi)
#pragma unroll
      for (int si = 0; si < 2; ++si)
#pragma unroll
        for (int r = 0; r < 4; ++r) s_acc[mi][si][r] = 0.f;

#pragma unroll
    for (int ks = 0; ks < 2; ++ks) {
      bf16x8 bk[2];
#pragma unroll
      for (int si = 0; si < 2; ++si) {
        const int srow = j * 32 + si * 16 + l15;
        const int kel = ks * 32 + lg * 8;
        bk[si] = *reinterpret_cast<const bf16x8*>(
            Kls + srow * 64 + (kel ^ ((srow & 7) << 3)));
      }
#pragma unroll
      for (int mi = 0; mi < 2; ++mi)
#pragma unroll
        for (int si = 0; si < 2; ++si)
          s_acc[mi][si] = __builtin_amdgcn_mfma_f32_16x16x32_bf16(
              a_q[mi][ks], bk[si], s_acc[mi][si], 0, 0, 0);
    }

    const bool diag = (j == qt);
#pragma unroll
    for (int mi = 0; mi < 2; ++mi) {
#pragma unroll
      for (int r = 0; r < 4; ++r) {
        const int mloc = mi * 16 + lg * 4 + r;
        float v0 = s_acc[mi][0][r] * 0.125f;
        float v1 = s_acc[mi][1][r] * 0.125f;
        if (diag) {
          if (l15 > mloc) v0 = -3.0e38f;
          if (16 + l15 > mloc) v1 = -3.0e38f;
        }
        float pm = fmaxf(v0, v1);
        pm = fmaxf(pm, __shfl_xor(pm, 1, 16));
        pm = fmaxf(pm, __shfl_xor(pm, 2, 16));
        pm = fmaxf(pm, __shfl_xor(pm, 4, 16));
        pm = fmaxf(pm, __shfl_xor(pm, 8, 16));
        const float mnew = fmaxf(mrun[mi][r], pm);
        const float alpha = __expf(mrun[mi][r] - mnew);
        mrun[mi][r] = mnew;
        const float p0 = __expf(v0 - mnew);
        const float p1 = __expf(v1 - mnew);
        float ps = p0 + p1;
        ps += __shfl_xor(ps, 1, 16);
        ps += __shfl_xor(ps, 2, 16);
        ps += __shfl_xor(ps, 4, 16);
        ps += __shfl_xor(ps, 8, 16);
        lrun[mi][r] = lrun[mi][r] * alpha + ps;
#pragma unroll
        for (int hi = 0; hi < 4; ++hi) o[mi][hi][r] *= alpha;
        Pw[mloc * 40 + l15] = f2bf(p0);
        Pw[mloc * 40 + 16 + l15] = f2bf(p1);
      }
    }

    bf16x8 pa[2];
#pragma unroll
    for (int mt = 0; mt < 2; ++mt)
      pa[mt] = *reinterpret_cast<const bf16x8*>(
          Pw + (mt * 16 + l15) * 40 + lg * 8);
#pragma unroll
    for (int hi = 0; hi < 4; ++hi) {
      const int h = hi * 16 + l15;
      const int sel = j * 32 + lg * 8;
      const bf16x8 bv = *reinterpret_cast<const bf16x8*>(
          Vtls + h * 256 + (sel ^ ((h & 7) << 3)));
#pragma unroll
      for (int mt = 0; mt < 2; ++mt)
        o[mt][hi] = __builtin_amdgcn_mfma_f32_16x16x32_bf16(
            pa[mt], bv, o[mt][hi], 0, 0, 0);
    }
  }

  // ---- out store ----
  float* og = out + ((size_t)b * NT + q0) * NH;
#pragma unroll
  for (int mi = 0; mi < 2; ++mi)
#pragma unroll
    for (int r = 0; r < 4; ++r) {
      const float inv = 1.f / lrun[mi][r];
      const int m = mi * 16 + lg * 4 + r;
#pragma unroll
      for (int hi = 0; hi < 4; ++hi)
        og[m * 64 + hi * 16 + l15] = o[mi][hi][r] * inv;
    }
}

// ---------------------------------------------------------------------------
extern "C" void kernel_launch(void* const* d_in, const int* in_sizes, int n_in,
                              void* d_out, int out_size, void* d_ws,
                              size_t ws_size, hipStream_t stream) {
  const float* x  = (const float*)d_in[0];
  const float* Wq = (const float*)d_in[1];
  const float* Wk = (const float*)d_in[2];
  const float* Wv = (const float*)d_in[3];
  unsigned short* Wt = (unsigned short*)d_ws;  // 147 KB
  float* out = (float*)d_out;

  w_transpose_kernel<<<dim3((WT_ELEMS + 255) / 256), dim3(256), 0, stream>>>(
      Wq, Wk, Wv, Wt);
  fused_qkv_attn_kernel<<<dim3(NB), dim3(512), 0, stream>>>(x, Wt, out);
}